// Round 1
// baseline (544.071 us; speedup 1.0000x reference)
//
#include <hip/hip_runtime.h>

#define HIDDEN 32
#define FF 40
#define SEQ_T 512

typedef __attribute__((ext_vector_type(8))) short short8;
typedef __attribute__((ext_vector_type(4))) float float4v;
typedef __attribute__((ext_vector_type(4))) unsigned uint4v;
typedef __attribute__((ext_vector_type(2))) unsigned uint2v;

// ---------------------------------------------------------------------------
// R10: fully fused single-wave recurrence. One wave per 16-row batch tile does
// BOTH matmuls (hh m-tiles 0-2, ho m-tiles 3-5) sharing one set of B-frags in
// registers. No __syncthreads anywhere; ring is a depth-2 ping-pong (9216 B).
// u and bias-1.0 live IN the ring (k=40,41; k>=42 zeroed once), so the k-half-1
// B-frag is a plain ds_read_b128 -- no cndmask injection. The ho finish
// (sigmoid+dot+store of step t-1) runs under the frag-read latency of step t.
// hi/lo planes packed with v_cvt_pk_bf16_f32 (RNE). Precision scheme (3-term
// split hi/lo bf16) identical to R9.
// ---------------------------------------------------------------------------

__global__ __launch_bounds__(256, 1) void rnn_prep(
    const float* __restrict__ W1hh, const float* __restrict__ b1hh,
    const float* __restrict__ W2hh, const float* __restrict__ b2hh,
    const float* __restrict__ W1ho, const float* __restrict__ b1ho,
    unsigned short* __restrict__ acatT_hi, unsigned short* __restrict__ acatT_lo)
{
    const int idx = blockIdx.x * 256 + threadIdx.x;
    if (idx >= 96 * 64) return;
    const int m = idx >> 6, k = idx & 63;
    const bool hh = m < 48;
    const int col = hh ? m : m - 48;
    float val = 0.f;
    if (col < FF) {
        const float* W1 = hh ? W1hh : W1ho;
        const float* b1 = hh ? b1hh : b1ho;
        if (k < FF) {
            for (int i = 0; i < HIDDEN; ++i)
                val = __builtin_fmaf(W2hh[k * HIDDEN + i], W1[i * FF + col], val);
        } else if (k == 40) {
            val = W1[HIDDEN * FF + col];
        } else if (k == 41) {
            val = b1[col];
            for (int i = 0; i < HIDDEN; ++i)
                val = __builtin_fmaf(b2hh[i], W1[i * FF + col], val);
        }
    }
    const unsigned vb = __builtin_bit_cast(unsigned, val);
    const unsigned short hi = (unsigned short)(vb >> 16);
    const float hif = __builtin_bit_cast(float, (unsigned)hi << 16);
    const float lo = val - hif;
    const unsigned lb = __builtin_bit_cast(unsigned, lo);
    const unsigned short los = (unsigned short)((lb + 0x7FFFu + ((lb >> 16) & 1u)) >> 16);
    acatT_hi[idx] = hi;
    acatT_lo[idx] = los;
}

__device__ __forceinline__ float sigmoid_fast(float x) {
    const float e = __builtin_amdgcn_exp2f(-x * 1.44269504088896341f);
    return __builtin_amdgcn_rcpf(1.0f + e);
}

// dword [hi16(v) : round-bf16(v - hi)] packer (for u-channel ring write)
__device__ __forceinline__ unsigned splitpack(float v) {
    const unsigned b = __builtin_bit_cast(unsigned, v);
    const unsigned hif = b & 0xFFFF0000u;
    const float rr = v - __builtin_bit_cast(float, hif);
    unsigned rb = __builtin_bit_cast(unsigned, rr) + 0x8000u;
    return __builtin_amdgcn_perm(b, rb, 0x07060302u);
}

// packs [bf16(hi) : bf16(lo)] with RNE; lo lands in the LOW ushort
__device__ __forceinline__ unsigned cvt_pk_bf16(float lo, float hi) {
    unsigned r;
    asm("v_cvt_pk_bf16_f32 %0, %1, %2" : "=v"(r) : "v"(lo), "v"(hi));
    return r;
}

__global__ __launch_bounds__(64, 1) void rnn_main(
    const float* __restrict__ inputs,
    const unsigned short* __restrict__ acatT_hi,
    const unsigned short* __restrict__ acatT_lo,
    const float* __restrict__ W1hh, const float* __restrict__ b1hh,
    const float* __restrict__ W1ho, const float* __restrict__ b1ho,
    const float* __restrict__ W2ho, const float* __restrict__ b2ho,
    float* __restrict__ ys)
{
    __shared__ unsigned short ring[2][2][16][72];   // 9216 B depth-2 ping-pong

    const int l = threadIdx.x;       // 64 threads = 1 wave per block
    const int r = l & 15;            // batch row within tile
    const int g = l >> 4;            // quad
    const size_t rowbase = (size_t)(blockIdx.x * 16 + r) * SEQ_T;
    const float* __restrict__ in_row = inputs + rowbase;

    // zero the ring once: k rows 42..71 must read as 0 forever (single wave,
    // same-wave LDS ordering -> no barrier needed)
    {
        uint4v* p = (uint4v*)&ring[0][0][0][0];
        const uint4v z4 = {0u, 0u, 0u, 0u};
#pragma unroll
        for (int i = 0; i < 9; ++i) p[l + 64 * i] = z4;   // 576 dwordx4 = 9216 B
    }

    // ---- A-frags: 6 m-tiles (0-2 hh, 3-5 ho), 2 k-halves, hi+lo planes ----
    short8 Ah[6][2], Al[6][2];
#pragma unroll
    for (int mt = 0; mt < 6; ++mt)
#pragma unroll
        for (int ks = 0; ks < 2; ++ks) {
            const int off = (mt * 16 + r) * 64 + ks * 32 + g * 8;
            Ah[mt][ks] = *(const short8*)(acatT_hi + off);
            Al[mt][ks] = *(const short8*)(acatT_lo + off);
        }

    float w2o_l[3][4];
#pragma unroll
    for (int mt = 0; mt < 3; ++mt)
#pragma unroll
        for (int q = 0; q < 4; ++q) {
            const int j = 16 * mt + 4 * g + q;
            w2o_l[mt][q] = (j < FF) ? W2ho[j] : 0.f;
        }
    const float b2o = b2ho[0];
    const bool wr2   = (g < 2);    // mt2 stores only k 32..39 (don't clobber u/bias)
    const bool wu    = (g == 0);   // one lane-quad writes the u/bias dword
    const bool out16 = (l < 16);

    // sigmoid + 2-plane split-pack + ring store (S rows k 0..39, u at k 40,
    // bias 1.0 at k 41)
    auto store_s = [&](int slot, const float4v (&z)[3], unsigned upk) {
        unsigned* bh = (unsigned*)&ring[slot][0][r][0];
        unsigned* bl = (unsigned*)&ring[slot][1][r][0];
#pragma unroll
        for (int mt = 0; mt < 3; ++mt) {
            const float s0 = sigmoid_fast(z[mt][0]);
            const float s1 = sigmoid_fast(z[mt][1]);
            const float s2 = sigmoid_fast(z[mt][2]);
            const float s3 = sigmoid_fast(z[mt][3]);
            const unsigned h01 = cvt_pk_bf16(s0, s1);
            const unsigned h23 = cvt_pk_bf16(s2, s3);
            const float r0 = s0 - __builtin_bit_cast(float, h01 << 16);
            const float r1 = s1 - __builtin_bit_cast(float, h01 & 0xFFFF0000u);
            const float r2 = s2 - __builtin_bit_cast(float, h23 << 16);
            const float r3 = s3 - __builtin_bit_cast(float, h23 & 0xFFFF0000u);
            const unsigned l01 = cvt_pk_bf16(r0, r1);
            const unsigned l23 = cvt_pk_bf16(r2, r3);
            if (mt < 2 || wr2) {
                uint2v hp, lp;
                hp.x = h01; hp.y = h23;
                lp.x = l01; lp.y = l23;
                *(uint2v*)(bh + 8 * mt + 2 * g) = hp;
                *(uint2v*)(bl + 8 * mt + 2 * g) = lp;
            }
        }
        if (wu) {
            bh[20] = (upk >> 16) | 0x3F800000u;   // [u_hi : bf16(1.0)]
            bl[20] = upk & 0xFFFFu;               // [u_lo : 0]
        }
    };

    // ---- prologue: t = 0 (z from u0 directly; h0 = 0) ----
    float4v accO[3];
    float uc;
    {
        const float u0 = in_row[0];
        float4v zh[3];
#pragma unroll
        for (int mt = 0; mt < 3; ++mt)
#pragma unroll
            for (int q = 0; q < 4; ++q) {
                const int n = 16 * mt + 4 * g + q;
                const int nc = n < FF ? n : FF - 1;
                zh[mt][q]   = __builtin_fmaf(u0, W1hh[HIDDEN * FF + nc], b1hh[nc]);
                accO[mt][q] = __builtin_fmaf(u0, W1ho[HIDDEN * FF + nc], b1ho[nc]);
            }
        store_s(0, zh, splitpack(in_row[1]));   // slot 0 = S(0) + u(1)
        uc = in_row[2];                         // u(t+1) for iter t=1
    }

    // ---- main loop: one fused step per iteration, zero barriers ----
    for (int t = 1; t < SEQ_T; ++t) {
        // B-frags of S_ext(t-1): 4x ds_read_b128, k-half-1 straight from ring
        const int sl = (t - 1) & 1;
        const unsigned short* ph = &ring[sl][0][r][0];
        const unsigned short* pl = &ring[sl][1][r][0];
        const short8 f0h = *(const short8*)(ph + g * 8);
        const short8 f0l = *(const short8*)(pl + g * 8);
        const short8 f1h = *(const short8*)(ph + 32 + g * 8);
        const short8 f1l = *(const short8*)(pl + 32 + g * 8);

        // prefetch u(t+2)
        int tn = t + 2; tn = tn < SEQ_T ? tn : SEQ_T - 1;
        const float un = in_row[tn];

        // finish output o(t-1) while the frag reads are in flight
        {
            float op = 0.f;
#pragma unroll
            for (int mt = 0; mt < 3; ++mt)
#pragma unroll
                for (int q = 0; q < 4; ++q)
                    op = __builtin_fmaf(sigmoid_fast(accO[mt][q]), w2o_l[mt][q], op);
            op += __shfl_xor(op, 16);
            op += __shfl_xor(op, 32);
            if (out16) ys[rowbase + (t - 1)] = op + b2o;
        }

        // 36 MFMAs: hh tiles first so their accs complete earliest
        float4v zh[3];
#pragma unroll
        for (int mt = 0; mt < 3; ++mt) {
            float4v a = {0.f, 0.f, 0.f, 0.f};
            a = __builtin_amdgcn_mfma_f32_16x16x32_bf16(Ah[mt][0], f0h, a, 0, 0, 0);
            a = __builtin_amdgcn_mfma_f32_16x16x32_bf16(Ah[mt][0], f0l, a, 0, 0, 0);
            a = __builtin_amdgcn_mfma_f32_16x16x32_bf16(Al[mt][0], f0h, a, 0, 0, 0);
            a = __builtin_amdgcn_mfma_f32_16x16x32_bf16(Ah[mt][1], f1h, a, 0, 0, 0);
            a = __builtin_amdgcn_mfma_f32_16x16x32_bf16(Ah[mt][1], f1l, a, 0, 0, 0);
            a = __builtin_amdgcn_mfma_f32_16x16x32_bf16(Al[mt][1], f1h, a, 0, 0, 0);
            zh[mt] = a;
        }
#pragma unroll
        for (int mt = 0; mt < 3; ++mt) {
            float4v a = {0.f, 0.f, 0.f, 0.f};
            a = __builtin_amdgcn_mfma_f32_16x16x32_bf16(Ah[mt + 3][0], f0h, a, 0, 0, 0);
            a = __builtin_amdgcn_mfma_f32_16x16x32_bf16(Ah[mt + 3][0], f0l, a, 0, 0, 0);
            a = __builtin_amdgcn_mfma_f32_16x16x32_bf16(Al[mt + 3][0], f0h, a, 0, 0, 0);
            a = __builtin_amdgcn_mfma_f32_16x16x32_bf16(Ah[mt + 3][1], f1h, a, 0, 0, 0);
            a = __builtin_amdgcn_mfma_f32_16x16x32_bf16(Ah[mt + 3][1], f1l, a, 0, 0, 0);
            a = __builtin_amdgcn_mfma_f32_16x16x32_bf16(Al[mt + 3][1], f1h, a, 0, 0, 0);
            accO[mt] = a;
        }

        // S(t) + u(t+1) into the other slot; ho finish deferred to next iter
        store_s(t & 1, zh, splitpack(uc));
        uc = un;
    }

    // ---- epilogue: output o(511) ----
    {
        float op = 0.f;
#pragma unroll
        for (int mt = 0; mt < 3; ++mt)
#pragma unroll
            for (int q = 0; q < 4; ++q)
                op = __builtin_fmaf(sigmoid_fast(accO[mt][q]), w2o_l[mt][q], op);
        op += __shfl_xor(op, 16);
        op += __shfl_xor(op, 32);
        if (out16) ys[rowbase + (SEQ_T - 1)] = op + b2o;
    }
}

extern "C" void kernel_launch(void* const* d_in, const int* in_sizes, int n_in,
                              void* d_out, int out_size, void* d_ws, size_t ws_size,
                              hipStream_t stream) {
    const float* inputs = (const float*)d_in[0];
    const float* W1hh   = (const float*)d_in[1];
    const float* b1hh   = (const float*)d_in[2];
    const float* W2hh   = (const float*)d_in[3];
    const float* b2hh   = (const float*)d_in[4];
    const float* W1ho   = (const float*)d_in[5];
    const float* b1ho   = (const float*)d_in[6];
    const float* W2ho   = (const float*)d_in[7];
    const float* b2ho   = (const float*)d_in[8];
    float* ys = (float*)d_out;

    unsigned short* acatT_hi = (unsigned short*)d_ws;     // 96*64 ushorts
    unsigned short* acatT_lo = acatT_hi + 96 * 64;

    const int B = in_sizes[0] / SEQ_T;   // 16384

    rnn_prep<<<(96 * 64 + 255) / 256, 256, 0, stream>>>(
        W1hh, b1hh, W2hh, b2hh, W1ho, b1ho, acatT_hi, acatT_lo);

    const int blocks = B / 16;           // 1024 blocks x 1 fused wave
    rnn_main<<<blocks, 64, 0, stream>>>(
        inputs, acatT_hi, acatT_lo, W1hh, b1hh, W1ho, b1ho, W2ho, b2ho, ys);
}

// Round 2
// 402.885 us; speedup vs baseline: 1.3504x; 1.3504x over previous
//
#include <hip/hip_runtime.h>

#define HIDDEN 32
#define FF 40
#define SEQ_T 512
#define RD 8     // ring depth; producer/consumer slot distance (disjoint mod 8)

typedef __attribute__((ext_vector_type(8))) short short8;
typedef __attribute__((ext_vector_type(4))) float float4v;
typedef __attribute__((ext_vector_type(2))) unsigned uint2v;

// ---------------------------------------------------------------------------
// R11 = R9's 2-wave decoupled structure (2 waves/SIMD, issue-saturated) with
// R10's work reductions + K=128 packed 3-term MFMA:
//   B-row k-layout (128 slots): [0..39]=S_hi | [40..79]=S_lo | [80..119]=S_hi
//   dup | [120..125]=(u_hi,1.0h,u_lo,0,u_hi,1.0h) | [126,127]=pad (A'=0).
//   A' mirrors: [Ah | Ah | Al | Ah_u,Ah_b,Ah_u,Ah_b,Al_u,Al_b | 0,0].
//   -> 4 MFMAs per m-tile (12/wave-step) instead of 6 (18), identical product
//   set as the verified 6-MFMA scheme (same roundings, same terms).
// u/bias live in the ring (producer writes u(t+1)), so B-frags are 4 plain
// ds_read_b128 -- no cndmask injection, no consumer-side u path.
// wave0 = hh producer, steps [3p+1..3p+3]; wave1 = ho consumer, [3p-2..3p];
// one barrier per 3 steps; ring slots written/read provably disjoint mod 8.
// ---------------------------------------------------------------------------

__global__ __launch_bounds__(256, 1) void rnn_prep(
    const float* __restrict__ W1hh, const float* __restrict__ b1hh,
    const float* __restrict__ W2hh, const float* __restrict__ b2hh,
    const float* __restrict__ W1ho, const float* __restrict__ b1ho,
    unsigned short* __restrict__ acatP)
{
    const int idx = blockIdx.x * 256 + threadIdx.x;
    if (idx >= 96 * 128) return;
    const int mrow = idx >> 7, s = idx & 127;

    // slot -> (contraction col, plane): plane 0 = hi(trunc), 1 = lo(RNE)
    int kcol, plane;
    if (s < 40)       { kcol = s;            plane = 0; }
    else if (s < 80)  { kcol = s - 40;       plane = 0; }  // A-side of S_lo region is Ah
    else if (s < 120) { kcol = s - 80;       plane = 1; }  // Al x S_hi-dup
    else if (s < 124) { kcol = 40 + (s & 1); plane = 0; }  // Ah_u, Ah_b (x u_hi,1 and u_lo,0)
    else if (s < 126) { kcol = 40 + (s & 1); plane = 1; }  // Al_u, Al_b (x u_hi,1)
    else { acatP[idx] = 0; return; }

    const bool hh = mrow < 48;
    const int col = hh ? mrow : mrow - 48;
    float val = 0.f;
    if (col < FF) {
        const float* W1 = hh ? W1hh : W1ho;
        const float* b1 = hh ? b1hh : b1ho;
        if (kcol < FF) {
            for (int i = 0; i < HIDDEN; ++i)
                val = __builtin_fmaf(W2hh[kcol * HIDDEN + i], W1[i * FF + col], val);
        } else if (kcol == 40) {
            val = W1[HIDDEN * FF + col];
        } else {  // kcol == 41: folded bias channel
            val = b1[col];
            for (int i = 0; i < HIDDEN; ++i)
                val = __builtin_fmaf(b2hh[i], W1[i * FF + col], val);
        }
    }
    const unsigned vb = __builtin_bit_cast(unsigned, val);
    const unsigned short hi = (unsigned short)(vb >> 16);
    unsigned short out;
    if (plane == 0) {
        out = hi;
    } else {
        const float hif = __builtin_bit_cast(float, (unsigned)hi << 16);
        const float lo = val - hif;
        const unsigned lb = __builtin_bit_cast(unsigned, lo);
        out = (unsigned short)((lb + 0x7FFFu + ((lb >> 16) & 1u)) >> 16);
    }
    acatP[idx] = out;
}

__device__ __forceinline__ float sigmoid_fast(float x) {
    const float e = __builtin_amdgcn_exp2f(-x * 1.44269504088896341f);
    return __builtin_amdgcn_rcpf(1.0f + e);
}

// dword [hi16(v) : round-bf16(v - hi)] packer (u-channel)
__device__ __forceinline__ unsigned splitpack(float v) {
    const unsigned b = __builtin_bit_cast(unsigned, v);
    const unsigned hif = b & 0xFFFF0000u;
    const float rr = v - __builtin_bit_cast(float, hif);
    unsigned rb = __builtin_bit_cast(unsigned, rr) + 0x8000u;
    return __builtin_amdgcn_perm(b, rb, 0x07060302u);
}

// packs [bf16(hi) : bf16(lo)] with RNE; first operand lands in the LOW ushort
__device__ __forceinline__ unsigned cvt_pk_bf16(float lo, float hi) {
    unsigned r;
    asm("v_cvt_pk_bf16_f32 %0, %1, %2" : "=v"(r) : "v"(lo), "v"(hi));
    return r;
}

__global__ __launch_bounds__(128, 2) void rnn_main(
    const float* __restrict__ inputs,
    const unsigned short* __restrict__ acatP,
    const float* __restrict__ W1hh, const float* __restrict__ b1hh,
    const float* __restrict__ W1ho, const float* __restrict__ b1ho,
    const float* __restrict__ W2ho, const float* __restrict__ b2ho,
    float* __restrict__ ys)
{
    // 136-ushort rows (272 B): 16B-aligned for b128 reads; slots 128..135 pad
    __shared__ __align__(16) unsigned short ring[RD][16][136];   // 34816 B

    const int tid = threadIdx.x;
    const int wv  = __builtin_amdgcn_readfirstlane(tid >> 6);  // 0=hh, 1=ho
    const int l = tid & 63;
    const int r = l & 15;        // batch row within tile
    const int g = l >> 4;        // quad
    const size_t rowbase = (size_t)(blockIdx.x * 16 + r) * SEQ_T;
    const float* __restrict__ in_row = inputs + rowbase;

    // ---- A-frags: this wave's 3 m-tiles, K=128 packed layout ----
    short8 A[3][4];
    const int mb = wv * 3;
#pragma unroll
    for (int mt = 0; mt < 3; ++mt)
#pragma unroll
        for (int ks = 0; ks < 4; ++ks)
            A[mt][ks] = *(const short8*)(acatP + ((mb + mt) * 16 + r) * 128 + ks * 32 + g * 8);

    float w2o_l[3][4];
#pragma unroll
    for (int mt = 0; mt < 3; ++mt)
#pragma unroll
        for (int q = 0; q < 4; ++q) {
            const int j = 16 * mt + 4 * g + q;
            w2o_l[mt][q] = (j < FF) ? W2ho[j] : 0.f;
        }
    const float b2o = b2ho[0];
    const bool out16 = (l < 16);

    auto load_frags = [&](int sl, short8 (&f)[4]) {
        const unsigned short* p = &ring[sl][r][0];
#pragma unroll
        for (int ks = 0; ks < 4; ++ks)
            f[ks] = *(const short8*)(p + ks * 32 + g * 8);
    };

    auto do_mfma = [&](const short8 (&f)[4], float4v (&acc)[3]) {
#pragma unroll
        for (int mt = 0; mt < 3; ++mt) acc[mt] = (float4v)0.f;
#pragma unroll
        for (int mt = 0; mt < 3; ++mt)
#pragma unroll
            for (int ks = 0; ks < 4; ++ks)
                acc[mt] = __builtin_amdgcn_mfma_f32_16x16x32_bf16(A[mt][ks], f[ks], acc[mt], 0, 0, 0);
    };

    // sigmoid + split-pack + ring store: hi@slot 4j, lo@40+4j, hi-dup@80+4j,
    // u/bias dwords @ slots 120..125 (written by the idle g==3 quad)
    auto store_s = [&](int slot, const float4v (&z)[3], unsigned upk) {
        unsigned* bp = (unsigned*)&ring[slot][r][0];
#pragma unroll
        for (int mt = 0; mt < 3; ++mt) {
            const float s0 = sigmoid_fast(z[mt][0]);
            const float s1 = sigmoid_fast(z[mt][1]);
            const float s2 = sigmoid_fast(z[mt][2]);
            const float s3 = sigmoid_fast(z[mt][3]);
            const unsigned h01 = cvt_pk_bf16(s0, s1);
            const unsigned h23 = cvt_pk_bf16(s2, s3);
            const float r0 = s0 - __builtin_bit_cast(float, h01 << 16);
            const float r1 = s1 - __builtin_bit_cast(float, h01 & 0xFFFF0000u);
            const float r2 = s2 - __builtin_bit_cast(float, h23 << 16);
            const float r3 = s3 - __builtin_bit_cast(float, h23 & 0xFFFF0000u);
            const unsigned l01 = cvt_pk_bf16(r0, r1);
            const unsigned l23 = cvt_pk_bf16(r2, r3);
            const int j = 4 * mt + g;
            if (j < 10) {
                uint2v hp, lp;
                hp.x = h01; hp.y = h23;
                lp.x = l01; lp.y = l23;
                *(uint2v*)(bp + 2 * j) = hp;        // S_hi
                *(uint2v*)(bp + 20 + 2 * j) = lp;   // S_lo
                *(uint2v*)(bp + 40 + 2 * j) = hp;   // S_hi dup
            }
        }
        if (g == 3) {
            uint2v up;
            up.x = (upk >> 16) | 0x3F800000u;   // [u_hi : bf16(1.0)]
            up.y = upk & 0xFFFFu;               // [u_lo : 0]
            *(uint2v*)(bp + 60) = up;           // slots 120..123
            bp[62] = up.x;                      // slots 124,125 (dup for Al)
        }
    };

    // ---- prologue: t = 0 ----
    float uc[3];
    {
        const float u0 = in_row[0];
        if (wv == 0) {
            float4v z[3];
#pragma unroll
            for (int mt = 0; mt < 3; ++mt)
#pragma unroll
                for (int q = 0; q < 4; ++q) {
                    const int n = 16 * mt + 4 * g + q;
                    const int nc = n < FF ? n : FF - 1;
                    z[mt][q] = __builtin_fmaf(u0, W1hh[HIDDEN * FF + nc], b1hh[nc]);
                }
            store_s(0, z, splitpack(in_row[1]));   // slot 0 = S(0) + u(1)
            uc[0] = in_row[2]; uc[1] = in_row[3]; uc[2] = in_row[4];
        } else {
            float op = 0.f;
#pragma unroll
            for (int mt = 0; mt < 3; ++mt)
#pragma unroll
                for (int q = 0; q < 4; ++q) {
                    const int n = 16 * mt + 4 * g + q;
                    const int nc = n < FF ? n : FF - 1;
                    const float so = sigmoid_fast(
                        __builtin_fmaf(u0, W1ho[HIDDEN * FF + nc], b1ho[nc]));
                    op = __builtin_fmaf(so, w2o_l[mt][q], op);
                }
            op += __shfl_xor(op, 16);
            op += __shfl_xor(op, 32);
            if (out16) ys[rowbase] = op + b2o;
            uc[0] = uc[1] = uc[2] = 0.f;
        }
    }
    __syncthreads();

    // ---- phase loop: wave0 runs steps [3p+1..3p+3], wave1 [3p-2..3p] ----
    for (int p = 0; p < 172; ++p) {
        if (wv == 0) {
            const int tb = 3 * p + 1;
            float un[3];
#pragma unroll
            for (int i = 0; i < 3; ++i) {
                int tn = tb + 4 + i; tn = tn < SEQ_T ? tn : SEQ_T - 1;
                un[i] = in_row[tn];     // u(3(p+1)+2+i) for next phase
            }
#pragma unroll
            for (int i = 0; i < 3; ++i) {
                const int t = tb + i;
                if (t < SEQ_T) {
                    short8 f[4];
                    load_frags((t - 1) & (RD - 1), f);
                    float4v z[3];
                    do_mfma(f, z);
                    store_s(t & (RD - 1), z, splitpack(uc[i]));
                }
            }
            uc[0] = un[0]; uc[1] = un[1]; uc[2] = un[2];
        } else {
            const int tb = 3 * p - 2;
#pragma unroll
            for (int i = 0; i < 3; ++i) {
                const int t = tb + i;
                if (t >= 1 && t < SEQ_T) {
                    short8 f[4];
                    load_frags((t - 1) & (RD - 1), f);
                    float4v acc[3];
                    do_mfma(f, acc);
                    float op = 0.f;
#pragma unroll
                    for (int mt = 0; mt < 3; ++mt)
#pragma unroll
                        for (int q = 0; q < 4; ++q)
                            op = __builtin_fmaf(sigmoid_fast(acc[mt][q]),
                                                w2o_l[mt][q], op);
                    op += __shfl_xor(op, 16);
                    op += __shfl_xor(op, 32);
                    if (out16) ys[rowbase + t] = op + b2o;
                }
            }
        }
        __syncthreads();
    }
}

extern "C" void kernel_launch(void* const* d_in, const int* in_sizes, int n_in,
                              void* d_out, int out_size, void* d_ws, size_t ws_size,
                              hipStream_t stream) {
    const float* inputs = (const float*)d_in[0];
    const float* W1hh   = (const float*)d_in[1];
    const float* b1hh   = (const float*)d_in[2];
    const float* W2hh   = (const float*)d_in[3];
    const float* b2hh   = (const float*)d_in[4];
    const float* W1ho   = (const float*)d_in[5];
    const float* b1ho   = (const float*)d_in[6];
    const float* W2ho   = (const float*)d_in[7];
    const float* b2ho   = (const float*)d_in[8];
    float* ys = (float*)d_out;

    unsigned short* acatP = (unsigned short*)d_ws;    // 96*128 ushorts

    const int B = in_sizes[0] / SEQ_T;   // 16384

    rnn_prep<<<(96 * 128 + 255) / 256, 256, 0, stream>>>(
        W1hh, b1hh, W2hh, b2hh, W1ho, b1ho, acatP);

    const int blocks = B / 16;           // 1024 blocks x 2 waves (hh + ho)
    rnn_main<<<blocks, 128, 0, stream>>>(
        inputs, acatP, W1hh, b1hh, W1ho, b1ho, W2ho, b2ho, ys);
}